// Round 1
// baseline (521.061 us; speedup 1.0000x reference)
//
#include <hip/hip_runtime.h>
#include <hip/hip_bf16.h>
#include <stdint.h>

#define S_LEN 2048
#define D_DIM 64
#define QBLK  64   // q rows per block
#define KVBLK 64   // kv rows per iteration
#define WAVES 4
#define QW    16   // q rows per wave

typedef __attribute__((ext_vector_type(8))) short bf16x8;
typedef __attribute__((ext_vector_type(4))) float f32x4;

__device__ __forceinline__ short f2bf(float f) {
    uint32_t u = __builtin_bit_cast(uint32_t, f);
    u += 0x7FFFu + ((u >> 16) & 1u);   // RNE
    return (short)(u >> 16);
}

// load 8 consecutive floats, scale, convert to bf16x8 fragment
__device__ __forceinline__ bf16x8 load8_bf16(const float* __restrict__ src, float scale) {
    f32x4 a = *(const f32x4*)(src);
    f32x4 b = *(const f32x4*)(src + 4);
    bf16x8 r;
    #pragma unroll
    for (int j = 0; j < 4; ++j) r[j]     = f2bf(a[j] * scale);
    #pragma unroll
    for (int j = 0; j < 4; ++j) r[4 + j] = f2bf(b[j] * scale);
    return r;
}

__global__ __launch_bounds__(256, 4)
void attn_fwd_kernel(const float* __restrict__ Q, const float* __restrict__ K,
                     const float* __restrict__ V, float* __restrict__ Out)
{
    const int qb   = blockIdx.x;   // 0..31
    const int bh   = blockIdx.y;   // 0..63
    const int tid  = threadIdx.x;
    const int wid  = tid >> 6;
    const int lane = tid & 63;
    const int lq   = lane & 15;    // 0..15
    const int lg   = lane >> 4;    // 0..3

    const int qbase = qb * QBLK;
    const int qw0   = qbase + wid * QW;

    const float* Qp = Q + (size_t)bh * S_LEN * D_DIM;
    const float* Kp = K + (size_t)bh * S_LEN * D_DIM;
    const float* Vp = V + (size_t)bh * S_LEN * D_DIM;
    float*       Op = Out + (size_t)bh * S_LEN * D_DIM;

    __shared__ __align__(16) short Vt[D_DIM][KVBLK + 8];          // V transposed, bf16
    __shared__ __align__(16) short Plds[WAVES][QW][KVBLK + 8];    // P per wave, bf16

    // ---- Q fragments, pre-scaled by 1/sqrt(D) ----
    bf16x8 qfrag[2];
    {
        const int row = qw0 + lq;
        #pragma unroll
        for (int c = 0; c < 2; ++c)
            qfrag[c] = load8_bf16(Qp + (size_t)row * D_DIM + c * 32 + lg * 8, 0.125f);
    }

    f32x4 acc[4];
    #pragma unroll
    for (int t = 0; t < 4; ++t) acc[t] = (f32x4)0.f;
    float m[4], l[4];
    #pragma unroll
    for (int r = 0; r < 4; ++r) { m[r] = -1e30f; l[r] = 0.f; }

    const int nkv = qb + 1;   // causal: kv blocks 0..qb
    for (int kb = 0; kb < nkv; ++kb) {
        const int kv0 = kb * KVBLK;

        __syncthreads();  // previous Vt fully consumed
        // ---- stage V tile transposed into LDS (block-cooperative) ----
        #pragma unroll
        for (int it = 0; it < 4; ++it) {
            int idx = tid + it * 256;          // 0..1023 float4s
            int row = idx >> 4;                // kv 0..63
            int c4  = idx & 15;                // d-quad 0..15
            f32x4 vv = *(const f32x4*)(Vp + (size_t)(kv0 + row) * D_DIM + c4 * 4);
            #pragma unroll
            for (int j = 0; j < 4; ++j)
                Vt[c4 * 4 + j][row] = f2bf(vv[j]);
        }
        __syncthreads();

        if (kv0 <= qw0 + QW - 1) {
            // ---- QK^T ----
            f32x4 s[4];
            #pragma unroll
            for (int t = 0; t < 4; ++t) s[t] = (f32x4)0.f;
            #pragma unroll
            for (int t = 0; t < 4; ++t) {
                const int krow = kv0 + t * 16 + lq;
                #pragma unroll
                for (int c = 0; c < 2; ++c) {
                    bf16x8 kf = load8_bf16(Kp + (size_t)krow * D_DIM + c * 32 + lg * 8, 1.0f);
                    s[t] = __builtin_amdgcn_mfma_f32_16x16x32_bf16(qfrag[c], kf, s[t], 0, 0, 0);
                }
            }
            // ---- causal mask (only on diagonal-crossing tiles) ----
            if (kv0 + KVBLK - 1 > qw0) {
                #pragma unroll
                for (int t = 0; t < 4; ++t) {
                    const int kvc = kv0 + t * 16 + lq;
                    #pragma unroll
                    for (int r = 0; r < 4; ++r) {
                        const int qr = qw0 + lg * 4 + r;
                        if (kvc > qr) s[t][r] = -1e30f;
                    }
                }
            }
            // ---- online softmax ----
            #pragma unroll
            for (int r = 0; r < 4; ++r) {
                float v0 = fmaxf(fmaxf(s[0][r], s[1][r]), fmaxf(s[2][r], s[3][r]));
                v0 = fmaxf(v0, __shfl_xor(v0, 1));
                v0 = fmaxf(v0, __shfl_xor(v0, 2));
                v0 = fmaxf(v0, __shfl_xor(v0, 4));
                v0 = fmaxf(v0, __shfl_xor(v0, 8));
                float mn = fmaxf(m[r], v0);
                float f  = __expf(m[r] - mn);
                m[r] = mn;
                l[r] *= f;
                #pragma unroll
                for (int t = 0; t < 4; ++t) acc[t][r] *= f;
            }
            // p = exp(s - m); stash bf16 P in LDS (wave-local region)
            #pragma unroll
            for (int t = 0; t < 4; ++t) {
                #pragma unroll
                for (int r = 0; r < 4; ++r) {
                    float p = __expf(s[t][r] - m[r]);
                    s[t][r] = p;
                    Plds[wid][lg * 4 + r][t * 16 + lq] = f2bf(p);
                }
            }
            #pragma unroll
            for (int r = 0; r < 4; ++r) {
                float rs = s[0][r] + s[1][r] + s[2][r] + s[3][r];
                rs += __shfl_xor(rs, 1);
                rs += __shfl_xor(rs, 2);
                rs += __shfl_xor(rs, 4);
                rs += __shfl_xor(rs, 8);
                l[r] += rs;
            }
            // ---- PV ----  (A = P[16x64] via LDS, B = Vt)
            #pragma unroll
            for (int c = 0; c < 2; ++c) {
                bf16x8 pf = *(const bf16x8*)&Plds[wid][lq][c * 32 + lg * 8];
                #pragma unroll
                for (int t = 0; t < 4; ++t) {
                    bf16x8 vf = *(const bf16x8*)&Vt[t * 16 + lq][c * 32 + lg * 8];
                    acc[t] = __builtin_amdgcn_mfma_f32_16x16x32_bf16(pf, vf, acc[t], 0, 0, 0);
                }
            }
        }
    }

    // ---- epilogue: O = acc / l ----
    #pragma unroll
    for (int r = 0; r < 4; ++r) {
        const int qr = qw0 + lg * 4 + r;
        const float inv = 1.f / l[r];
        #pragma unroll
        for (int t = 0; t < 4; ++t)
            Op[(size_t)qr * D_DIM + t * 16 + lq] = acc[t][r] * inv;
    }
}

extern "C" void kernel_launch(void* const* d_in, const int* in_sizes, int n_in,
                              void* d_out, int out_size, void* d_ws, size_t ws_size,
                              hipStream_t stream) {
    const float* q = (const float*)d_in[0];
    const float* k = (const float*)d_in[1];
    const float* v = (const float*)d_in[2];
    // d_in[3] is the causal tril mask; masking is done analytically.
    float* out = (float*)d_out;

    dim3 grid(S_LEN / QBLK, 4 * 16 /* B*H */);
    dim3 block(256);
    attn_fwd_kernel<<<grid, block, 0, stream>>>(q, k, v, out);
}